// Round 1
// baseline (121.048 us; speedup 1.0000x reference)
//
#include <hip/hip_runtime.h>

#define WIN   11
#define HALO  10          // WIN-1
#define TW    64          // output tile width
#define TH    8           // output tile height
#define IW    512
#define IH    512
#define OW    502         // 512 - 10
#define OH    502
#define NCH   48          // 16*3 channel-images
#define SW    (TW + HALO) // 74: staged tile width
#define SH    (TH + HALO) // 18: staged tile height

// Grid: x = x-tiles (8), y = y-tiles (63), z = channel-images (48)
__global__ __launch_bounds__(256)
void ssim_tile_kernel(const float* __restrict__ img1,
                      const float* __restrict__ img2,
                      const float* __restrict__ win,
                      float* __restrict__ partial)
{
    __shared__ float s1[SH * SW];
    __shared__ float s2[SH * SW];
    // vertical-blur intermediates for the 5 quantities
    __shared__ float v_m1[TH * SW];
    __shared__ float v_m2[TH * SW];
    __shared__ float v_11[TH * SW];
    __shared__ float v_22[TH * SW];
    __shared__ float v_12[TH * SW];
    __shared__ float w[WIN];
    __shared__ float wavesum[4];

    const int tid = threadIdx.x;
    if (tid < WIN) w[tid] = win[tid];

    const int ch = blockIdx.z;
    const int x0 = blockIdx.x * TW;
    const int y0 = blockIdx.y * TH;
    const float* __restrict__ p1 = img1 + (size_t)ch * IW * IH;
    const float* __restrict__ p2 = img2 + (size_t)ch * IW * IH;

    // ---- stage input tiles (clamped loads; clamped values feed only masked-out outputs)
    for (int i = tid; i < SH * SW; i += 256) {
        int r = i / SW;
        int c = i - r * SW;
        int gy = y0 + r; if (gy > IH - 1) gy = IH - 1;
        int gx = x0 + c; if (gx > IW - 1) gx = IW - 1;
        size_t gidx = (size_t)gy * IW + gx;
        s1[i] = p1[gidx];
        s2[i] = p2[gidx];
    }
    __syncthreads();

    // ---- vertical blur of the 5 products
    for (int i = tid; i < TH * SW; i += 256) {
        int r = i / SW;
        int c = i - r * SW;
        float m1 = 0.f, m2 = 0.f, q11 = 0.f, q22 = 0.f, q12 = 0.f;
        int base = r * SW + c;
#pragma unroll
        for (int k = 0; k < WIN; ++k) {
            float wk = w[k];
            float a = s1[base + k * SW];
            float b = s2[base + k * SW];
            m1  = fmaf(wk, a, m1);
            m2  = fmaf(wk, b, m2);
            q11 = fmaf(wk * a, a, q11);
            q22 = fmaf(wk * b, b, q22);
            q12 = fmaf(wk * a, b, q12);
        }
        v_m1[i] = m1; v_m2[i] = m2;
        v_11[i] = q11; v_22[i] = q22; v_12[i] = q12;
    }
    __syncthreads();

    // ---- horizontal blur + SSIM + per-thread accumulate
    const float c1 = 0.0001f;   // (0.01*1.0)^2
    const float c2 = 0.0009f;   // (0.03*1.0)^2
    float acc = 0.f;
    for (int i = tid; i < TH * TW; i += 256) {
        int r = i / TW;
        int c = i - r * TW;
        int oy = y0 + r, ox = x0 + c;
        if (oy < OH && ox < OW) {
            float m1 = 0.f, m2 = 0.f, q11 = 0.f, q22 = 0.f, q12 = 0.f;
            int base = r * SW + c;
#pragma unroll
            for (int k = 0; k < WIN; ++k) {
                float wk = w[k];
                m1  = fmaf(wk, v_m1[base + k], m1);
                m2  = fmaf(wk, v_m2[base + k], m2);
                q11 = fmaf(wk, v_11[base + k], q11);
                q22 = fmaf(wk, v_22[base + k], q22);
                q12 = fmaf(wk, v_12[base + k], q12);
            }
            float mu1_sq = m1 * m1, mu2_sq = m2 * m2, mu12 = m1 * m2;
            float s11 = q11 - mu1_sq;
            float s22 = q22 - mu2_sq;
            float s12 = q12 - mu12;
            float cs   = (2.f * s12 + c2) / (s11 + s22 + c2);
            float ssim = (2.f * mu12 + c1) / (mu1_sq + mu2_sq + c1) * cs;
            acc += ssim;
        }
    }

    // ---- block reduction (wave64 shuffle, then 4 wave leaders)
#pragma unroll
    for (int off = 32; off > 0; off >>= 1)
        acc += __shfl_down(acc, off, 64);
    if ((tid & 63) == 0) wavesum[tid >> 6] = acc;
    __syncthreads();
    if (tid == 0) {
        float s = wavesum[0] + wavesum[1] + wavesum[2] + wavesum[3];
        partial[(size_t)blockIdx.z * (gridDim.x * gridDim.y)
                + blockIdx.y * gridDim.x + blockIdx.x] = s;
    }
}

__global__ __launch_bounds__(256)
void reduce_partials_kernel(const float* __restrict__ partial, int n,
                            float* __restrict__ out, double inv_count)
{
    __shared__ double sd[256];
    double s = 0.0;
    for (int i = threadIdx.x; i < n; i += 256)
        s += (double)partial[i];
    sd[threadIdx.x] = s;
    __syncthreads();
    for (int off = 128; off > 0; off >>= 1) {
        if (threadIdx.x < off) sd[threadIdx.x] += sd[threadIdx.x + off];
        __syncthreads();
    }
    if (threadIdx.x == 0)
        out[0] = (float)(sd[0] * inv_count);
}

extern "C" void kernel_launch(void* const* d_in, const int* in_sizes, int n_in,
                              void* d_out, int out_size, void* d_ws, size_t ws_size,
                              hipStream_t stream)
{
    const float* img1 = (const float*)d_in[0];
    const float* img2 = (const float*)d_in[1];
    const float* win  = (const float*)d_in[2];
    float* out = (float*)d_out;
    float* partial = (float*)d_ws;

    const int gx = (OW + TW - 1) / TW;   // 8
    const int gy = (OH + TH - 1) / TH;   // 63
    dim3 grid(gx, gy, NCH);              // 8 x 63 x 48 = 24192 blocks
    dim3 block(256);

    ssim_tile_kernel<<<grid, block, 0, stream>>>(img1, img2, win, partial);

    const int nblocks = gx * gy * NCH;
    const double inv_count = 1.0 / ((double)NCH * OW * OH);
    reduce_partials_kernel<<<1, 256, 0, stream>>>(partial, nblocks, out, inv_count);
}

// Round 2
// 81.734 us; speedup vs baseline: 1.4810x; 1.4810x over previous
//
#include <hip/hip_runtime.h>

#define WIN   11
#define IW    512
#define IH    512
#define OW    502         // 512 - 10
#define OH    502
#define NCH   48          // 16*3 channel-images
#define TW    64          // output tile width
#define TH    16          // output tile height
#define SWP   76          // staged columns: 64+10=74, padded to 76 for float4 align
#define NSTRIP (TH/4)     // 4 row-strips of 4
#define NTASK (SWP*NSTRIP) // 304 vertical-blur tasks

// Grid: x = 8 x-tiles, y = 32 y-tiles, z = 48 channel-images
__global__ __launch_bounds__(256)
void ssim_fused_kernel(const float* __restrict__ img1,
                       const float* __restrict__ img2,
                       const float* __restrict__ win,
                       float* __restrict__ partial)
{
    // vertical-blur results for 5 quantities; row stride 76 floats = 304 B (16B aligned)
    __shared__ __align__(16) float v[5][TH][SWP];
    __shared__ float wavesum[4];

    const int tid = threadIdx.x;
    const int ch = blockIdx.z;
    const int x0 = blockIdx.x * TW;
    const int y0 = blockIdx.y * TH;
    const float* __restrict__ p1 = img1 + (size_t)ch * (IW * IH);
    const float* __restrict__ p2 = img2 + (size_t)ch * (IW * IH);

    // Gaussian weights -> uniform (scalar) registers
    float w[WIN];
#pragma unroll
    for (int k = 0; k < WIN; ++k) w[k] = win[k];

    // ---- Phase V: vertical blur of the 5 products, direct from global.
    // Task = (strip s of 4 output rows, column c). 15 input rows held in regs.
    for (int i = tid; i < NTASK; i += 256) {
        int s = i / SWP;
        int c = i - s * SWP;
        int gx = x0 + c; if (gx > IW - 1) gx = IW - 1;
        int r0 = s * 4;
        float a[15], b[15];
#pragma unroll
        for (int j = 0; j < 15; ++j) {
            int gy = y0 + r0 + j; if (gy > IH - 1) gy = IH - 1;
            size_t gidx = (size_t)gy * IW + gx;
            a[j] = p1[gidx];
            b[j] = p2[gidx];
        }
#pragma unroll
        for (int r = 0; r < 4; ++r) {
            float m1 = 0.f, m2 = 0.f, q11 = 0.f, q22 = 0.f, q12 = 0.f;
#pragma unroll
            for (int k = 0; k < WIN; ++k) {
                float wk = w[k];
                float av = a[r + k], bv = b[r + k];
                float wa = wk * av, wb = wk * bv;
                m1 += wa;
                m2 += wb;
                q11 = fmaf(wa, av, q11);
                q22 = fmaf(wb, bv, q22);
                q12 = fmaf(wa, bv, q12);
            }
            v[0][r0 + r][c] = m1;
            v[1][r0 + r][c] = m2;
            v[2][r0 + r][c] = q11;
            v[3][r0 + r][c] = q22;
            v[4][r0 + r][c] = q12;
        }
    }
    __syncthreads();

    // ---- Phase H: horizontal blur + SSIM. Thread = (row r, x-group g of 4 pixels).
    const int g = tid & 15;     // x-group 0..15 -> xs = 4g
    const int r = tid >> 4;     // row 0..15
    const int xs = g * 4;
    const float c1 = 0.0001f;   // (0.01*1.0)^2
    const float c2 = 0.0009f;   // (0.03*1.0)^2

    float res[5][4];
#pragma unroll
    for (int q = 0; q < 5; ++q) {
        const float* row = &v[q][r][0];
        float4 A = *reinterpret_cast<const float4*>(row + xs);
        float4 B = *reinterpret_cast<const float4*>(row + xs + 4);
        float4 C = *reinterpret_cast<const float4*>(row + xs + 8);
        float4 D = *reinterpret_cast<const float4*>(row + xs + 12);
        float x[16] = {A.x, A.y, A.z, A.w, B.x, B.y, B.z, B.w,
                       C.x, C.y, C.z, C.w, D.x, D.y, D.z, D.w};
#pragma unroll
        for (int o = 0; o < 4; ++o) {
            float sacc = 0.f;
#pragma unroll
            for (int k = 0; k < WIN; ++k)
                sacc = fmaf(w[k], x[o + k], sacc);
            res[q][o] = sacc;
        }
    }

    float acc = 0.f;
    const int oy = y0 + r;
    if (oy < OH) {
#pragma unroll
        for (int o = 0; o < 4; ++o) {
            int ox = x0 + xs + o;
            if (ox < OW) {
                float m1 = res[0][o], m2 = res[1][o];
                float q11 = res[2][o], q22 = res[3][o], q12 = res[4][o];
                float mu1_sq = m1 * m1, mu2_sq = m2 * m2, mu12 = m1 * m2;
                float s11 = q11 - mu1_sq;
                float s22 = q22 - mu2_sq;
                float s12 = q12 - mu12;
                float cs   = (2.f * s12 + c2) / (s11 + s22 + c2);
                float ssim = (2.f * mu12 + c1) / (mu1_sq + mu2_sq + c1) * cs;
                acc += ssim;
            }
        }
    }

    // ---- block reduction (wave64 shuffle, then 4 wave leaders)
#pragma unroll
    for (int off = 32; off > 0; off >>= 1)
        acc += __shfl_down(acc, off, 64);
    if ((tid & 63) == 0) wavesum[tid >> 6] = acc;
    __syncthreads();
    if (tid == 0) {
        float s = wavesum[0] + wavesum[1] + wavesum[2] + wavesum[3];
        partial[(size_t)blockIdx.z * (gridDim.x * gridDim.y)
                + blockIdx.y * gridDim.x + blockIdx.x] = s;
    }
}

__global__ __launch_bounds__(256)
void reduce_partials_kernel(const float* __restrict__ partial, int n,
                            float* __restrict__ out, double inv_count)
{
    __shared__ double sd[256];
    double s = 0.0;
    for (int i = threadIdx.x; i < n; i += 256)
        s += (double)partial[i];
    sd[threadIdx.x] = s;
    __syncthreads();
    for (int off = 128; off > 0; off >>= 1) {
        if (threadIdx.x < off) sd[threadIdx.x] += sd[threadIdx.x + off];
        __syncthreads();
    }
    if (threadIdx.x == 0)
        out[0] = (float)(sd[0] * inv_count);
}

extern "C" void kernel_launch(void* const* d_in, const int* in_sizes, int n_in,
                              void* d_out, int out_size, void* d_ws, size_t ws_size,
                              hipStream_t stream)
{
    const float* img1 = (const float*)d_in[0];
    const float* img2 = (const float*)d_in[1];
    const float* win  = (const float*)d_in[2];
    float* out = (float*)d_out;
    float* partial = (float*)d_ws;

    const int gx = (OW + TW - 1) / TW;   // 8
    const int gy = (OH + TH - 1) / TH;   // 32
    dim3 grid(gx, gy, NCH);              // 8 x 32 x 48 = 12288 blocks
    dim3 block(256);

    ssim_fused_kernel<<<grid, block, 0, stream>>>(img1, img2, win, partial);

    const int nblocks = gx * gy * NCH;
    const double inv_count = 1.0 / ((double)NCH * OW * OH);
    reduce_partials_kernel<<<1, 256, 0, stream>>>(partial, nblocks, out, inv_count);
}

// Round 3
// 80.266 us; speedup vs baseline: 1.5081x; 1.0183x over previous
//
#include <hip/hip_runtime.h>

#define WIN   11
#define IW    512
#define IH    512
#define OW    502         // 512 - 10
#define OH    502
#define NCH   48          // 16*3 channel-images
#define TW    128         // output tile width
#define TH    16          // output tile height
#define SWP   140         // staged columns: 128+10=138, padded to 140 (16B align)
#define NSTRIP 2          // two 8-row strips
#define NTASK (SWP*NSTRIP) // 280 vertical-blur tasks

__device__ __forceinline__ float fast_rcp(float x) {
    return __builtin_amdgcn_rcpf(x);   // v_rcp_f32, ~1 ulp
}

template<bool EDGE>
__device__ __forceinline__ void ssim_tile(const float* __restrict__ p1,
                                          const float* __restrict__ p2,
                                          const float* __restrict__ w,
                                          float (*v)[TH][SWP],
                                          int x0, int y0, int tid, float& acc)
{
    // ---- Phase V: vertical blur of 5 products, direct from global.
    // Task = (strip s of 8 output rows, column c). 18 input rows in regs.
    for (int i = tid; i < NTASK; i += 256) {
        int s = (i >= SWP) ? 1 : 0;
        int c = i - s * SWP;
        int gx = x0 + c; if (EDGE) gx = min(gx, IW - 1);
        int r0 = s * 8;
        float a[18], b[18], aa[18], bb[18], ab[18];
#pragma unroll
        for (int j = 0; j < 18; ++j) {
            int gy = y0 + r0 + j; if (EDGE) gy = min(gy, IH - 1);
            int gidx = gy * IW + gx;
            float av = p1[gidx], bv = p2[gidx];
            a[j] = av; b[j] = bv;
            aa[j] = av * av; bb[j] = bv * bv; ab[j] = av * bv;
        }
#pragma unroll
        for (int r = 0; r < 8; ++r) {
            float m1 = 0.f, m2 = 0.f, q11 = 0.f, q22 = 0.f, q12 = 0.f;
#pragma unroll
            for (int k = 0; k < WIN; ++k) {
                float wk = w[k];
                m1  = fmaf(wk, a[r + k],  m1);
                m2  = fmaf(wk, b[r + k],  m2);
                q11 = fmaf(wk, aa[r + k], q11);
                q22 = fmaf(wk, bb[r + k], q22);
                q12 = fmaf(wk, ab[r + k], q12);
            }
            v[0][r0 + r][c] = m1;
            v[1][r0 + r][c] = m2;
            v[2][r0 + r][c] = q11;
            v[3][r0 + r][c] = q22;
            v[4][r0 + r][c] = q12;
        }
    }
    __syncthreads();

    // ---- Phase H: horizontal blur + SSIM.
    // Lane map: r = tid&15 (row), g = tid>>4 (x-group of 8 px).
    // Same-row lanes are 16 apart -> 2-way LDS bank aliasing only (free).
    const int r  = tid & 15;
    const int g  = tid >> 4;
    const int xs = g * 8;

    float res[5][8];
#pragma unroll
    for (int q = 0; q < 5; ++q) {
        const float* row = &v[q][r][0];
        float x[20];
#pragma unroll
        for (int t = 0; t < 5; ++t) {
            float4 f = *reinterpret_cast<const float4*>(row + xs + 4 * t);
            x[4 * t + 0] = f.x; x[4 * t + 1] = f.y;
            x[4 * t + 2] = f.z; x[4 * t + 3] = f.w;
        }
#pragma unroll
        for (int o = 0; o < 8; ++o) {
            float sacc = 0.f;
#pragma unroll
            for (int k = 0; k < WIN; ++k)
                sacc = fmaf(w[k], x[o + k], sacc);
            res[q][o] = sacc;
        }
    }

    const float c1 = 0.0001f;   // (0.01*1.0)^2
    const float c2 = 0.0009f;   // (0.03*1.0)^2
    const int oy = y0 + r;
#pragma unroll
    for (int o = 0; o < 8; ++o) {
        bool valid = !EDGE || (oy < OH && (x0 + xs + o) < OW);
        if (valid) {
            float m1 = res[0][o], m2 = res[1][o];
            float mu11 = m1 * m1, mu22 = m2 * m2, mu12 = m1 * m2;
            float s11 = res[2][o] - mu11;
            float s22 = res[3][o] - mu22;
            float s12 = res[4][o] - mu12;
            float num = (2.f * mu12 + c1) * (2.f * s12 + c2);
            float den = (mu11 + mu22 + c1) * (s11 + s22 + c2);
            acc += num * fast_rcp(den);
        }
    }
}

// Grid: x = 4 x-tiles, y = 32 y-tiles, z = 48 channel-images
__global__ __launch_bounds__(256)
void ssim_fused_kernel(const float* __restrict__ img1,
                       const float* __restrict__ img2,
                       const float* __restrict__ win,
                       float* __restrict__ partial)
{
    __shared__ __align__(16) float v[5][TH][SWP];
    __shared__ float wavesum[4];

    const int tid = threadIdx.x;
    const int ch = blockIdx.z;
    const int x0 = blockIdx.x * TW;
    const int y0 = blockIdx.y * TH;
    const float* __restrict__ p1 = img1 + (size_t)ch * (IW * IH);
    const float* __restrict__ p2 = img2 + (size_t)ch * (IW * IH);

    float w[WIN];
#pragma unroll
    for (int k = 0; k < WIN; ++k) w[k] = win[k];

    float acc = 0.f;
    const bool edge = (blockIdx.x == gridDim.x - 1) || (blockIdx.y == gridDim.y - 1);
    if (edge) ssim_tile<true >(p1, p2, w, v, x0, y0, tid, acc);
    else      ssim_tile<false>(p1, p2, w, v, x0, y0, tid, acc);

    // ---- block reduction (wave64 shuffle, then 4 wave leaders)
#pragma unroll
    for (int off = 32; off > 0; off >>= 1)
        acc += __shfl_down(acc, off, 64);
    if ((tid & 63) == 0) wavesum[tid >> 6] = acc;
    __syncthreads();
    if (tid == 0) {
        float s = wavesum[0] + wavesum[1] + wavesum[2] + wavesum[3];
        partial[(size_t)blockIdx.z * (gridDim.x * gridDim.y)
                + blockIdx.y * gridDim.x + blockIdx.x] = s;
    }
}

__global__ __launch_bounds__(256)
void reduce_partials_kernel(const float* __restrict__ partial, int n,
                            float* __restrict__ out, double inv_count)
{
    __shared__ double sd[256];
    double s = 0.0;
    for (int i = threadIdx.x; i < n; i += 256)
        s += (double)partial[i];
    sd[threadIdx.x] = s;
    __syncthreads();
    for (int off = 128; off > 0; off >>= 1) {
        if (threadIdx.x < off) sd[threadIdx.x] += sd[threadIdx.x + off];
        __syncthreads();
    }
    if (threadIdx.x == 0)
        out[0] = (float)(sd[0] * inv_count);
}

extern "C" void kernel_launch(void* const* d_in, const int* in_sizes, int n_in,
                              void* d_out, int out_size, void* d_ws, size_t ws_size,
                              hipStream_t stream)
{
    const float* img1 = (const float*)d_in[0];
    const float* img2 = (const float*)d_in[1];
    const float* win  = (const float*)d_in[2];
    float* out = (float*)d_out;
    float* partial = (float*)d_ws;

    const int gx = (OW + TW - 1) / TW;   // 4
    const int gy = (OH + TH - 1) / TH;   // 32
    dim3 grid(gx, gy, NCH);              // 4 x 32 x 48 = 6144 blocks
    dim3 block(256);

    ssim_fused_kernel<<<grid, block, 0, stream>>>(img1, img2, win, partial);

    const int nblocks = gx * gy * NCH;
    const double inv_count = 1.0 / ((double)NCH * OW * OH);
    reduce_partials_kernel<<<1, 256, 0, stream>>>(partial, nblocks, out, inv_count);
}

// Round 4
// 65.658 us; speedup vs baseline: 1.8436x; 1.2225x over previous
//
#include <hip/hip_runtime.h>

#define WIN   11
#define IW    512
#define IH    512
#define OW    502         // 512 - 10
#define OH    502
#define NCH   48          // 16*3 channel-images
#define TW    128         // output tile width
#define TH    16          // output tile height
#define SWP   140         // staged cols: 128+10=138 padded to mult-of-4 (b128 align)
#define SROWS 26          // TH + WIN - 1

__device__ __forceinline__ float fast_rcp(float x) {
    return __builtin_amdgcn_rcpf(x);   // v_rcp_f32, ~1 ulp
}

// Blurred planes: 0 = mu1, 1 = mu2, 2 = blur(a^2+b^2), 3 = blur(ab)
template<bool EDGE>
__device__ __forceinline__ void ssim_tile(const float* __restrict__ p1,
                                          const float* __restrict__ p2,
                                          const float* __restrict__ w,
                                          float (*v)[TH][SWP],
                                          int x0, int y0, int tid, float& acc)
{
    // ---- Phase V: one 26-row strip per column, streaming register accumulators.
    if (tid < SWP) {
        const int c = tid;
        int gx = x0 + c; if (EDGE) gx = min(gx, IW - 1);
        float am[4][TH];                      // 64 accumulator VGPRs
#pragma unroll
        for (int q = 0; q < 4; ++q)
#pragma unroll
            for (int r = 0; r < TH; ++r) am[q][r] = 0.f;

#pragma unroll
        for (int j = 0; j < SROWS; ++j) {
            int gy = y0 + j; if (EDGE) gy = min(gy, IH - 1);
            const int gidx = gy * IW + gx;
            float av = p1[gidx];
            float bv = p2[gidx];
            float s = av * av; s = fmaf(bv, bv, s);   // a^2 + b^2
            float t = av * bv;                        // a*b
            // output r = j - k, valid for 0 <= r < TH and 0 <= k < WIN
#pragma unroll
            for (int k = 0; k < WIN; ++k) {
                const int r = j - k;
                if (r >= 0 && r < TH) {               // static after unroll
                    float wk = w[k];
                    am[0][r] = fmaf(wk, av, am[0][r]);
                    am[1][r] = fmaf(wk, bv, am[1][r]);
                    am[2][r] = fmaf(wk, s,  am[2][r]);
                    am[3][r] = fmaf(wk, t,  am[3][r]);
                }
            }
        }
#pragma unroll
        for (int q = 0; q < 4; ++q)
#pragma unroll
            for (int r = 0; r < TH; ++r)
                v[q][r][c] = am[q][r];
    }
    __syncthreads();

    // ---- Phase H: horizontal blur + SSIM. Thread = (row r, x-group g of 8 px).
    const int r  = tid & 15;
    const int g  = tid >> 4;
    const int xs = g * 8;

    float res[4][8];
#pragma unroll
    for (int q = 0; q < 4; ++q) {
        const float* row = &v[q][r][0];
        float x[20];
#pragma unroll
        for (int t5 = 0; t5 < 5; ++t5) {
            float4 f = *reinterpret_cast<const float4*>(row + xs + 4 * t5);
            x[4*t5+0] = f.x; x[4*t5+1] = f.y;
            x[4*t5+2] = f.z; x[4*t5+3] = f.w;
        }
#pragma unroll
        for (int o = 0; o < 8; ++o) {
            float sacc = 0.f;
#pragma unroll
            for (int k = 0; k < WIN; ++k)
                sacc = fmaf(w[k], x[o + k], sacc);
            res[q][o] = sacc;
        }
    }

    const float c1 = 0.0001f;   // (0.01*1.0)^2
    const float c2 = 0.0009f;   // (0.03*1.0)^2
    const int oy = y0 + r;
#pragma unroll
    for (int o = 0; o < 8; ++o) {
        bool valid = !EDGE || (oy < OH && (x0 + xs + o) < OW);
        if (valid) {
            float m1 = res[0][o], m2 = res[1][o];
            float mu11 = m1 * m1, mu22 = m2 * m2, mu12 = m1 * m2;
            float sAB = res[2][o] - mu11 - mu22;   // s11 + s22
            float s12 = res[3][o] - mu12;
            float num = (2.f * mu12 + c1) * (2.f * s12 + c2);
            float den = (mu11 + mu22 + c1) * (sAB + c2);
            acc += num * fast_rcp(den);
        }
    }
}

// Grid: x = 4 x-tiles, y = 32 y-tiles, z = 48 channel-images
__global__ __launch_bounds__(256, 4)
void ssim_fused_kernel(const float* __restrict__ img1,
                       const float* __restrict__ img2,
                       const float* __restrict__ win,
                       float* __restrict__ partial)
{
    __shared__ __align__(16) float v[4][TH][SWP];
    __shared__ float wavesum[4];

    const int tid = threadIdx.x;
    const int ch = blockIdx.z;
    const int x0 = blockIdx.x * TW;
    const int y0 = blockIdx.y * TH;
    const float* __restrict__ p1 = img1 + (size_t)ch * (IW * IH);
    const float* __restrict__ p2 = img2 + (size_t)ch * (IW * IH);

    float w[WIN];
#pragma unroll
    for (int k = 0; k < WIN; ++k) w[k] = win[k];

    float acc = 0.f;
    const bool edge = (blockIdx.x == gridDim.x - 1) || (blockIdx.y == gridDim.y - 1);
    if (edge) ssim_tile<true >(p1, p2, w, v, x0, y0, tid, acc);
    else      ssim_tile<false>(p1, p2, w, v, x0, y0, tid, acc);

    // ---- block reduction (wave64 shuffle, then 4 wave leaders)
#pragma unroll
    for (int off = 32; off > 0; off >>= 1)
        acc += __shfl_down(acc, off, 64);
    if ((tid & 63) == 0) wavesum[tid >> 6] = acc;
    __syncthreads();
    if (tid == 0) {
        float s = wavesum[0] + wavesum[1] + wavesum[2] + wavesum[3];
        partial[(size_t)blockIdx.z * (gridDim.x * gridDim.y)
                + blockIdx.y * gridDim.x + blockIdx.x] = s;
    }
}

__global__ __launch_bounds__(256)
void reduce_partials_kernel(const float* __restrict__ partial, int n,
                            float* __restrict__ out, double inv_count)
{
    __shared__ double sd[256];
    double s = 0.0;
    for (int i = threadIdx.x; i < n; i += 256)
        s += (double)partial[i];
    sd[threadIdx.x] = s;
    __syncthreads();
    for (int off = 128; off > 0; off >>= 1) {
        if (threadIdx.x < off) sd[threadIdx.x] += sd[threadIdx.x + off];
        __syncthreads();
    }
    if (threadIdx.x == 0)
        out[0] = (float)(sd[0] * inv_count);
}

extern "C" void kernel_launch(void* const* d_in, const int* in_sizes, int n_in,
                              void* d_out, int out_size, void* d_ws, size_t ws_size,
                              hipStream_t stream)
{
    const float* img1 = (const float*)d_in[0];
    const float* img2 = (const float*)d_in[1];
    const float* win  = (const float*)d_in[2];
    float* out = (float*)d_out;
    float* partial = (float*)d_ws;

    const int gx = (OW + TW - 1) / TW;   // 4
    const int gy = (OH + TH - 1) / TH;   // 32
    dim3 grid(gx, gy, NCH);              // 4 x 32 x 48 = 6144 blocks
    dim3 block(256);

    ssim_fused_kernel<<<grid, block, 0, stream>>>(img1, img2, win, partial);

    const int nblocks = gx * gy * NCH;
    const double inv_count = 1.0 / ((double)NCH * OW * OH);
    reduce_partials_kernel<<<1, 256, 0, stream>>>(partial, nblocks, out, inv_count);
}

// Round 5
// 54.037 us; speedup vs baseline: 2.2401x; 1.2151x over previous
//
#include <hip/hip_runtime.h>

#define WIN   11
#define IW    512
#define IH    512
#define OW    502         // 512 - 10
#define OH    502
#define NCH   48          // 16*3 channel-images
#define TW    128         // output tile width
#define TH    16          // output tile height
#define SWC   138         // columns computed in V: TW + 10
#define SWP   142         // LDS row stride in float2 units (padding: bank spread, 16B align)
#define SROWS 26          // TH + WIN - 1

typedef float v2f __attribute__((ext_vector_type(2)));

__device__ __forceinline__ float fast_rcp(float x) {
    return __builtin_amdgcn_rcpf(x);   // v_rcp_f32, ~1 ulp
}

// ---- V phase: one streaming step (input row J), all indices compile-time ----
template<bool EDGE, int J>
__device__ __forceinline__ void vstep(const float* __restrict__ p1,
                                      const float* __restrict__ p2,
                                      int y0, int gx,
                                      v2f (&accA)[TH], v2f (&accB)[TH],
                                      const float (&w)[WIN])
{
    int gy = y0 + J;
    if (EDGE) gy = min(gy, IH - 1);
    const int gidx = gy * IW + gx;
    const float av = p1[gidx];
    const float bv = p2[gidx];
    v2f ab; ab.x = av; ab.y = bv;                       // pack A inputs: (a, b)
    v2f st; st.x = fmaf(av, av, bv * bv); st.y = av * bv; // pack B inputs: (a^2+b^2, ab)
#pragma unroll
    for (int k = 0; k < WIN; ++k) {
        const int r = J - k;                            // compile-time after unroll
        if (r >= 0 && r < TH) {
            v2f ws; ws.x = w[k]; ws.y = w[k];
            accA[r] = __builtin_elementwise_fma(ws, ab, accA[r]);
            accB[r] = __builtin_elementwise_fma(ws, st, accB[r]);
        }
    }
}

template<bool EDGE, int J>
struct VRec {
    static __device__ __forceinline__ void run(const float* __restrict__ p1,
                                               const float* __restrict__ p2,
                                               int y0, int gx,
                                               v2f (&accA)[TH], v2f (&accB)[TH],
                                               const float (&w)[WIN])
    {
        vstep<EDGE, J>(p1, p2, y0, gx, accA, accB, w);
        VRec<EDGE, J + 1>::run(p1, p2, y0, gx, accA, accB, w);
    }
};
template<bool EDGE>
struct VRec<EDGE, SROWS> {
    static __device__ __forceinline__ void run(const float* __restrict__,
                                               const float* __restrict__,
                                               int, int, v2f (&)[TH], v2f (&)[TH],
                                               const float (&)[WIN]) {}
};

template<bool EDGE>
__device__ __forceinline__ void ssim_tile(const float* __restrict__ p1,
                                          const float* __restrict__ p2,
                                          const float (&w)[WIN],
                                          v2f (*vbuf)[TH][SWP],
                                          int x0, int y0, int tid, float& acc)
{
    // ---- Phase V: streaming vertical blur, one column per thread, packed planes.
    if (tid < SWC) {
        const int c = tid;
        int gx = x0 + c;
        if (EDGE) gx = min(gx, IW - 1);
        v2f accA[TH], accB[TH];
#pragma unroll
        for (int r = 0; r < TH; ++r) {
            accA[r] = (v2f){0.f, 0.f};
            accB[r] = (v2f){0.f, 0.f};
        }
        VRec<EDGE, 0>::run(p1, p2, y0, gx, accA, accB, w);
#pragma unroll
        for (int r = 0; r < TH; ++r) {
            vbuf[0][r][c] = accA[r];
            vbuf[1][r][c] = accB[r];
        }
    }
    __syncthreads();

    // ---- Phase H: horizontal blur + SSIM. Thread = (row r, x-group g of 8 px).
    const int r  = tid & 15;
    const int g  = tid >> 4;
    const int xs = g * 8;

    v2f resA[8], resB[8];
#pragma unroll
    for (int q = 0; q < 2; ++q) {
        v2f x2[18];
        const float4* src = reinterpret_cast<const float4*>(&vbuf[q][r][xs]);
#pragma unroll
        for (int t = 0; t < 9; ++t) {
            float4 f = src[t];
            x2[2*t+0].x = f.x; x2[2*t+0].y = f.y;
            x2[2*t+1].x = f.z; x2[2*t+1].y = f.w;
        }
#pragma unroll
        for (int o = 0; o < 8; ++o) {
            v2f s = {0.f, 0.f};
#pragma unroll
            for (int k = 0; k < WIN; ++k) {
                v2f ws; ws.x = w[k]; ws.y = w[k];
                s = __builtin_elementwise_fma(ws, x2[o + k], s);
            }
            if (q == 0) resA[o] = s; else resB[o] = s;
        }
    }

    const float c1 = 0.0001f;   // (0.01*1.0)^2
    const float c2 = 0.0009f;   // (0.03*1.0)^2
    const int oy = y0 + r;
#pragma unroll
    for (int o = 0; o < 8; ++o) {
        bool valid = !EDGE || (oy < OH && (x0 + xs + o) < OW);
        if (valid) {
            float m1 = resA[o].x, m2 = resA[o].y;
            float mu11 = m1 * m1, mu22 = m2 * m2, mu12 = m1 * m2;
            float sAB = resB[o].x - mu11 - mu22;   // s11 + s22
            float s12 = resB[o].y - mu12;
            float num = (2.f * mu12 + c1) * (2.f * s12 + c2);
            float den = (mu11 + mu22 + c1) * (sAB + c2);
            acc += num * fast_rcp(den);
        }
    }
}

// Grid: x = 4 x-tiles, y = 32 y-tiles, z = 48 channel-images
__global__ __launch_bounds__(256, 4)
void ssim_fused_kernel(const float* __restrict__ img1,
                       const float* __restrict__ img2,
                       const float* __restrict__ win,
                       float* __restrict__ partial)
{
    __shared__ __align__(16) v2f vbuf[2][TH][SWP];   // 36,352 B
    __shared__ float wavesum[4];

    const int tid = threadIdx.x;
    const int ch = blockIdx.z;
    const int x0 = blockIdx.x * TW;
    const int y0 = blockIdx.y * TH;
    const float* __restrict__ p1 = img1 + (size_t)ch * (IW * IH);
    const float* __restrict__ p2 = img2 + (size_t)ch * (IW * IH);

    float w[WIN];
#pragma unroll
    for (int k = 0; k < WIN; ++k) w[k] = win[k];

    float acc = 0.f;
    const bool edge = (blockIdx.x == gridDim.x - 1) || (blockIdx.y == gridDim.y - 1);
    if (edge) ssim_tile<true >(p1, p2, w, vbuf, x0, y0, tid, acc);
    else      ssim_tile<false>(p1, p2, w, vbuf, x0, y0, tid, acc);

    // ---- block reduction (wave64 shuffle, then 4 wave leaders)
#pragma unroll
    for (int off = 32; off > 0; off >>= 1)
        acc += __shfl_down(acc, off, 64);
    if ((tid & 63) == 0) wavesum[tid >> 6] = acc;
    __syncthreads();
    if (tid == 0) {
        float s = wavesum[0] + wavesum[1] + wavesum[2] + wavesum[3];
        partial[(size_t)blockIdx.z * (gridDim.x * gridDim.y)
                + blockIdx.y * gridDim.x + blockIdx.x] = s;
    }
}

__global__ __launch_bounds__(256)
void reduce_partials_kernel(const float* __restrict__ partial, int n,
                            float* __restrict__ out, double inv_count)
{
    __shared__ double sd[256];
    double s = 0.0;
    for (int i = threadIdx.x; i < n; i += 256)
        s += (double)partial[i];
    sd[threadIdx.x] = s;
    __syncthreads();
    for (int off = 128; off > 0; off >>= 1) {
        if (threadIdx.x < off) sd[threadIdx.x] += sd[threadIdx.x + off];
        __syncthreads();
    }
    if (threadIdx.x == 0)
        out[0] = (float)(sd[0] * inv_count);
}

extern "C" void kernel_launch(void* const* d_in, const int* in_sizes, int n_in,
                              void* d_out, int out_size, void* d_ws, size_t ws_size,
                              hipStream_t stream)
{
    const float* img1 = (const float*)d_in[0];
    const float* img2 = (const float*)d_in[1];
    const float* win  = (const float*)d_in[2];
    float* out = (float*)d_out;
    float* partial = (float*)d_ws;

    const int gx = (OW + TW - 1) / TW;   // 4
    const int gy = (OH + TH - 1) / TH;   // 32
    dim3 grid(gx, gy, NCH);              // 4 x 32 x 48 = 6144 blocks
    dim3 block(256);

    ssim_fused_kernel<<<grid, block, 0, stream>>>(img1, img2, win, partial);

    const int nblocks = gx * gy * NCH;
    const double inv_count = 1.0 / ((double)NCH * OW * OH);
    reduce_partials_kernel<<<1, 256, 0, stream>>>(partial, nblocks, out, inv_count);
}